// Round 3
// baseline (332.017 us; speedup 1.0000x reference)
//
#include <hip/hip_runtime.h>
#include <math.h>

#define DEPTH   5
#define HIDDEN  128
#define CODE    400
#define NFREQ   9
#define BATCH   8
#define NPTS    262144
#define PTSB    64
#define BLOCK   256

typedef __attribute__((ext_vector_type(8))) short sh8;
typedef __attribute__((ext_vector_type(4))) float f32x4;
typedef __attribute__((ext_vector_type(4))) uint  u32x4;

struct CoefTab { float c[54]; };   // [s][yk] SH normalization, host-computed

__device__ __forceinline__ ushort f2bf(float f) {   // round-to-nearest-even
    union { float f; uint u; } v; v.f = f;
    uint r = v.u + 0x7fffu + ((v.u >> 16) & 1u);
    return (ushort)(r >> 16);
}

// ---------------------------------------------------------------------------
// Prep (identical to proven version).
// ---------------------------------------------------------------------------
__global__ void sinr_prep(const float* __restrict__ a,
                          const float* __restrict__ Wcode,
                          const float* __restrict__ bcode,
                          const float* __restrict__ bfwd,
                          const float* __restrict__ Wftr,
                          const float* __restrict__ bftr,
                          const float* __restrict__ Wfwd,
                          CoefTab ct,
                          float* __restrict__ cterm,
                          ushort* __restrict__ wfB,
                          ushort* __restrict__ gwB) {
    int blk = blockIdx.x, tid = threadIdx.x;
    if (blk < DEPTH * BATCH) {
        if (tid < HIDDEN) {
            int i = blk / BATCH, b = blk % BATCH, h = tid;
            const float* ar = a + b * CODE;
            const float* wr = Wcode + (i * HIDDEN + h) * CODE;
            float acc = bcode[i * HIDDEN + h] + bfwd[i * HIDDEN + h];
            for (int c = 0; c < CODE; c += 4) {
                float4 av = *(const float4*)(ar + c);
                float4 wv = *(const float4*)(wr + c);
                acc = fmaf(av.x, wv.x, acc);
                acc = fmaf(av.y, wv.y, acc);
                acc = fmaf(av.z, wv.z, acc);
                acc = fmaf(av.w, wv.w, acc);
            }
            cterm[(i * BATCH + b) * HIDDEN + h] = acc;
        }
    } else if (blk < DEPTH * BATCH + 192) {
        int e = (blk - DEPTH * BATCH) * BLOCK + tid;     // < 49152
        int j    = e & 7;
        int lane = (e >> 3) & 63;
        int t    = (e >> 9) & 1;
        int nt   = (e >> 10) & 7;
        int s    = e >> 13;                               // 0..5
        int g  = nt * 16 + (lane & 15);
        int kq = lane >> 4;
        float v = 0.0f;
        if (kq == 0 || kq == 2) {
            v = ct.c[s * 9 + j] * Wftr[(s * HIDDEN + g) * NFREQ + j];
        } else if (kq == 1) {
            if (j == 0 || j == 1)
                v = ct.c[s * 9 + 8] * Wftr[(s * HIDDEN + g) * NFREQ + 8];
            else if (j == 2)
                v = bftr[s * HIDDEN + g];
        }
        uint u = __float_as_uint(v);
        float rf = v - __uint_as_float(u & 0xFFFF0000u);
        wfB[e] = t ? f2bf(rf) : (ushort)(u >> 16);
    } else {
        int e = (blk - DEPTH * BATCH - 192) * BLOCK + tid;  // < 163840
        if (e < DEPTH * 4 * 8 * 2 * 512) {
            int j     = e & 7;
            int lane  = (e >> 3) & 63;
            int img   = (e >> 9) & 1;
            int nt    = (e >> 10) & 7;
            int kq    = (e >> 13) & 3;
            int layer = e >> 15;
            int g = nt * 16 + (lane & 15);
            int h = kq * 32 + (lane >> 4) * 8 + j;
            float v = Wfwd[(layer * HIDDEN + g) * HIDDEN + h];
            uint u = __float_as_uint(v);
            float rf = v - __uint_as_float(u & 0xFFFF0000u);
            gwB[e] = img ? f2bf(rf) : (ushort)(u >> 16);
        }
    }
}

// ---------------------------------------------------------------------------
// Main. ONLY change vs the 167us proven kernel: ypk is a 2-shift double
// buffer (6 KB instead of 18 KB -> LDS 38.9 KB -> 4 blocks/CU). Every wave
// still computes the full proven P/trig table and the verbatim pack loop.
// Shifts 0/1 go to LDS at init (waves 0/1); shifts 2..5 are packed at init
// into 12 regs on wave s&3 and stored to buffer s&1 during layer s-2 (that
// buffer's last reader, fphase(s-2), finished two barriers earlier).
// All arithmetic producing stored bits is byte-identical to the baseline.
// ---------------------------------------------------------------------------
__global__ __launch_bounds__(BLOCK, 4)
void sinr_main(const float* __restrict__ x,
               const ushort* __restrict__ wfB,
               const ushort* __restrict__ gwB,
               const float* __restrict__ cterm,
               const float* __restrict__ Wout,
               const float* __restrict__ boutp,
               float* __restrict__ out,
               float* __restrict__ out_x) {
    __shared__ __align__(16) ushort zh16[PTSB * HIDDEN];     // 16 KB
    __shared__ __align__(16) ushort zl16[PTSB * HIDDEN];     // 16 KB
    __shared__ __align__(16) ushort ypk[2 * 3 * PTSB * 8];   // 6 KB (dbuf)
    __shared__ __align__(16) ushort zrow[8];

    const int tid  = threadIdx.x;
    const int lane = tid & 63;
    const int w    = tid >> 6;
    const int l15  = lane & 15, lq = lane >> 4;
    const int p0   = blockIdx.x * PTSB;
    const int b    = p0 >> 15;

    if (tid < 2 * PTSB) out_x[p0 * 2 + tid] = x[p0 * 2 + tid];
    if (tid < 8) zrow[tid] = 0;

    // staged pre-packed shift (wave w owns shift: w==0->4, 1->5, 2->2, 3->3)
    sh8 pk0, pk1, pk2;

    // store one packed shift triple into ypk buffer `buf`
    auto ystore = [&](int buf, const sh8& k0, const sh8& k1, const sh8& k2) {
        int off = (buf * 3 * PTSB + lane) * 8;
        *(sh8*)&ypk[off]                = k0;
        *(sh8*)&ypk[off + PTSB * 8]     = k1;
        *(sh8*)&ypk[off + 2 * PTSB * 8] = k2;
    };

    // ---- harmonics: every wave computes the full proven P/trig table ------
    {
        float th = x[(p0 + lane) * 2 + 0];
        float ph = x[(p0 + lane) * 2 + 1];
        float c  = cosf(ph);
        float somx2 = sqrtf(fmaxf(1.0f - c * c, 0.0f));
        float s1, c1;
        sincosf(th, &s1, &c1);
        float ctab[5], stab[5];
        ctab[0] = 1.0f; stab[0] = 0.0f;
        ctab[1] = c1;   stab[1] = s1;
#pragma unroll
        for (int k = 2; k <= 4; ++k) {
            ctab[k] = ctab[k - 1] * c1 - stab[k - 1] * s1;
            stab[k] = stab[k - 1] * c1 + ctab[k - 1] * s1;
        }
        float P[5][6];
        float pmm = 1.0f;
#pragma unroll
        for (int am = 0; am <= 4; ++am) {
            if (am > 0) pmm *= -(2.0f * am - 1.0f) * somx2;
            float pm2 = pmm;
            float pm1 = c * (2.0f * am + 1.0f) * pmm;
            P[am][0] = pm2;
            P[am][1] = pm1;
#pragma unroll
            for (int s = 2; s < 6; ++s) {
                int l = am + s;
                float pl = ((2.0f * l - 1.0f) * c * pm1
                            - (float)(l + am - 1) * pm2) / (float)(l - am);
                P[am][s] = pl;
                pm2 = pm1;
                pm1 = pl;
            }
        }
        // verbatim proven pack loop, parameterized by the 5 P values
        auto mk = [&](float Pv0, float Pv1, float Pv2, float Pv3, float Pv4,
                      sh8& k0, sh8& k1, sh8& k2) {
            float Pv[5] = {Pv0, Pv1, Pv2, Pv3, Pv4};
            ushort yh[9], yl[9];
#pragma unroll
            for (int mm = -4; mm <= 4; ++mm) {
                int am = mm < 0 ? -mm : mm;
                float trig = (mm > 0) ? ctab[am] : ((mm < 0) ? stab[am] : 1.0f);
                float yv = Pv[am] * trig;
                uint u = __float_as_uint(yv);
                yh[mm + 4] = (ushort)(u >> 16);
                float rf = yv - __uint_as_float(u & 0xFFFF0000u);
                yl[mm + 4] = (ushort)(__float_as_uint(rf) >> 16);
            }
#pragma unroll
            for (int j = 0; j < 8; ++j) { k0[j] = (short)yh[j]; k2[j] = (short)yl[j]; }
            k1[0] = (short)yh[8]; k1[1] = (short)yl[8]; k1[2] = (short)0x3F80;
            k1[3] = 0; k1[4] = 0; k1[5] = 0; k1[6] = 0; k1[7] = 0;
        };
        sh8 t0, t1, t2;
        if (w == 0) {
            mk(P[0][0], P[1][0], P[2][0], P[3][0], P[4][0], t0, t1, t2);
            ystore(0, t0, t1, t2);
            mk(P[0][4], P[1][4], P[2][4], P[3][4], P[4][4], pk0, pk1, pk2);
        } else if (w == 1) {
            mk(P[0][1], P[1][1], P[2][1], P[3][1], P[4][1], t0, t1, t2);
            ystore(1, t0, t1, t2);
            mk(P[0][5], P[1][5], P[2][5], P[3][5], P[4][5], pk0, pk1, pk2);
        } else if (w == 2) {
            mk(P[0][2], P[1][2], P[2][2], P[3][2], P[4][2], pk0, pk1, pk2);
        } else {
            mk(P[0][3], P[1][3], P[2][3], P[3][3], P[4][3], pk0, pk1, pk2);
        }
    }
    __syncthreads();

    // z store: row = mt*16+lq*4+r, col h = (w*2+nt)*16+l15; split-bf16 trunc
    // (verbatim proven version)
    auto zstore = [&](int mt, int nt, int r, float val) {
        int row = mt * 16 + lq * 4 + r;
        int hh  = (w * 2 + nt) * 16 + l15;
        int idx = row * HIDDEN + ((((hh >> 3) ^ (row & 15))) << 3) + (hh & 7);
        uint u = __float_as_uint(val);
        zh16[idx] = (ushort)(u >> 16);
        float rf = val - __uint_as_float(u & 0xFFFF0000u);
        zl16[idx] = (ushort)(__float_as_uint(rf) >> 16);
    };

    // F phase for shift s -> facc[4][2]; reads ypk buffer (s&1)
    auto fphase = [&](int s, f32x4 (*facc)[2]) {
        sh8 wb1[2], wb2[2];
#pragma unroll
        for (int nt = 0; nt < 2; ++nt) {
            const ushort* wp = wfB + s * 8192 + (w * 2 + nt) * 1024 + lane * 8;
            wb1[nt] = *(const sh8*)wp;
            wb2[nt] = *(const sh8*)(wp + 512);
        }
#pragma unroll
        for (int mt = 0; mt < 4; ++mt) {
            const ushort* ya = (lq < 3)
                ? &ypk[(((s & 1) * 3 + lq) * PTSB + mt * 16 + l15) * 8]
                : &zrow[0];
            sh8 yf = *(const sh8*)ya;
#pragma unroll
            for (int nt = 0; nt < 2; ++nt) {
                f32x4 t = (f32x4){0.f, 0.f, 0.f, 0.f};
                t = __builtin_amdgcn_mfma_f32_16x16x32_bf16(yf, wb1[nt], t, 0, 0, 0);
                t = __builtin_amdgcn_mfma_f32_16x16x32_bf16(yf, wb2[nt], t, 0, 0, 0);
                facc[mt][nt] = t;
            }
        }
    };

    // ---- z init: z0 = F(sft=0) ---------------------------------------------
    {
        f32x4 f0[4][2];
        fphase(0, f0);
#pragma unroll
        for (int mt = 0; mt < 4; ++mt)
#pragma unroll
            for (int nt = 0; nt < 2; ++nt)
#pragma unroll
                for (int r = 0; r < 4; ++r)
                    zstore(mt, nt, r, f0[mt][nt][r]);
    }
    __syncthreads();

    // ---- 5 layers (2 barriers/layer) ---------------------------------------
    for (int layer = 0; layer < DEPTH; ++layer) {
        f32x4 facc[4][2];
        fphase(layer + 1, facc);

        // publish shift layer+2 (pre-packed regs) into buffer (layer+2)&1.
        // That buffer's last reader was fphase(layer), two barriers ago.
        if (layer < DEPTH - 1 && w == ((layer + 2) & 3))
            ystore((layer + 2) & 1, pk0, pk1, pk2);

        float ctv[2];
#pragma unroll
        for (int nt = 0; nt < 2; ++nt)
            ctv[nt] = cterm[(layer * BATCH + b) * HIDDEN + (w * 2 + nt) * 16 + l15];

        f32x4 acc[4][2];
#pragma unroll
        for (int mt = 0; mt < 4; ++mt)
#pragma unroll
            for (int nt = 0; nt < 2; ++nt)
                acc[mt][nt] = (f32x4){0.f, 0.f, 0.f, 0.f};

#pragma unroll
        for (int kq = 0; kq < 4; ++kq) {
            const ushort* gp = gwB + (layer * 4 + kq) * 8192 + lane * 8;
            sh8 bh0 = *(const sh8*)(gp + (w * 2 + 0) * 1024);
            sh8 bl0 = *(const sh8*)(gp + (w * 2 + 0) * 1024 + 512);
            sh8 bh1 = *(const sh8*)(gp + (w * 2 + 1) * 1024);
            sh8 bl1 = *(const sh8*)(gp + (w * 2 + 1) * 1024 + 512);
#pragma unroll
            for (int mt = 0; mt < 4; ++mt) {
                int row  = mt * 16 + l15;
                int base = row * HIDDEN + (((kq * 4 + lq) ^ l15) << 3);
                sh8 ah = *(const sh8*)&zh16[base];
                sh8 al = *(const sh8*)&zl16[base];
                acc[mt][0] = __builtin_amdgcn_mfma_f32_16x16x32_bf16(ah, bh0, acc[mt][0], 0, 0, 0);
                acc[mt][0] = __builtin_amdgcn_mfma_f32_16x16x32_bf16(al, bh0, acc[mt][0], 0, 0, 0);
                acc[mt][0] = __builtin_amdgcn_mfma_f32_16x16x32_bf16(ah, bl0, acc[mt][0], 0, 0, 0);
                acc[mt][1] = __builtin_amdgcn_mfma_f32_16x16x32_bf16(ah, bh1, acc[mt][1], 0, 0, 0);
                acc[mt][1] = __builtin_amdgcn_mfma_f32_16x16x32_bf16(al, bh1, acc[mt][1], 0, 0, 0);
                acc[mt][1] = __builtin_amdgcn_mfma_f32_16x16x32_bf16(ah, bl1, acc[mt][1], 0, 0, 0);
            }
        }
        __syncthreads();   // all z reads complete before overwrite

        // epilogue: z_next = (acc + ct) * F
#pragma unroll
        for (int mt = 0; mt < 4; ++mt)
#pragma unroll
            for (int nt = 0; nt < 2; ++nt)
#pragma unroll
                for (int r = 0; r < 4; ++r)
                    zstore(mt, nt, r, (acc[mt][nt][r] + ctv[nt]) * facc[mt][nt][r]);
        __syncthreads();   // writes visible before next layer's reads
    }

    // ---- final: out[p] = (zh+zl) · Wout + bout (psum overlays dead ypk) ----
    float* psum = (float*)ypk;
    {
        int p = lane, qd = w;
        float accf = 0.0f;
#pragma unroll
        for (int cc = 0; cc < 4; ++cc) {
            int chunk = qd * 4 + cc;
            int base  = p * HIDDEN + ((chunk ^ (p & 15)) << 3);
            u32x4 hv = *(const u32x4*)&zh16[base];
            u32x4 lv = *(const u32x4*)&zl16[base];
            uint uh[4] = {hv.x, hv.y, hv.z, hv.w};
            uint ul[4] = {lv.x, lv.y, lv.z, lv.w};
            const float* wp = Wout + chunk * 8;
#pragma unroll
            for (int q2 = 0; q2 < 4; ++q2) {
                float a0 = __uint_as_float(uh[q2] << 16)
                         + __uint_as_float(ul[q2] << 16);
                float a1 = __uint_as_float(uh[q2] & 0xFFFF0000u)
                         + __uint_as_float(ul[q2] & 0xFFFF0000u);
                accf = fmaf(a0, wp[q2 * 2], accf);
                accf = fmaf(a1, wp[q2 * 2 + 1], accf);
            }
        }
        psum[qd * 64 + p] = accf;
    }
    __syncthreads();
    if (tid < PTSB) {
        out[p0 + tid] = boutp[0] + psum[tid] + psum[64 + tid]
                                 + psum[128 + tid] + psum[192 + tid];
    }
}

// ---------------------------------------------------------------------------
extern "C" void kernel_launch(void* const* d_in, const int* in_sizes, int n_in,
                              void* d_out, int out_size, void* d_ws, size_t ws_size,
                              hipStream_t stream) {
    (void)in_sizes; (void)n_in; (void)out_size; (void)ws_size;
    const float* x     = (const float*)d_in[0];
    const float* a     = (const float*)d_in[1];
    const float* Wftr  = (const float*)d_in[2];
    const float* bftr  = (const float*)d_in[3];
    const float* Wfwd  = (const float*)d_in[4];
    const float* bfwd  = (const float*)d_in[5];
    const float* Wcode = (const float*)d_in[6];
    const float* bcode = (const float*)d_in[7];
    const float* Wout  = (const float*)d_in[8];
    const float* bout  = (const float*)d_in[9];

    float* out   = (float*)d_out;                    // [B*N]
    float* out_x = out + NPTS;                       // [B*N*2]
    float*  cterm = (float*)d_ws;                    // 5120 floats
    ushort* wfB = (ushort*)(cterm + DEPTH * BATCH * HIDDEN);  // 49152 ushorts
    ushort* gwB = wfB + 49152;                                // 163840 ushorts

    // SH normalization coefficients on host (deterministic per call)
    CoefTab ct;
    for (int s = 0; s < 6; ++s)
        for (int yk = 0; yk < 9; ++yk) {
            int mm = yk - 4, am = mm < 0 ? -mm : mm, l = am + s;
            double ratio = 1.0;
            for (int q = l - am + 1; q <= l + am; ++q) ratio *= (double)q;
            double norm = sqrt((2.0 * l + 1.0) / (4.0 * M_PI * ratio));
            double cf = (mm == 0) ? norm : ((am & 1) ? -1.0 : 1.0) * sqrt(2.0) * norm;
            ct.c[s * 9 + yk] = (float)cf;
        }

    int nprep = DEPTH * BATCH + 192 + 640;
    sinr_prep<<<nprep, BLOCK, 0, stream>>>(a, Wcode, bcode, bfwd, Wftr, bftr,
                                           Wfwd, ct, cterm, wfB, gwB);
    sinr_main<<<NPTS / PTSB, BLOCK, 0, stream>>>(
        x, wfB, gwB, cterm, Wout, bout, out, out_x);
}

// Round 4
// 219.661 us; speedup vs baseline: 1.5115x; 1.5115x over previous
//
#include <hip/hip_runtime.h>
#include <math.h>

#define DEPTH   5
#define HIDDEN  128
#define CODE    400
#define NFREQ   9
#define BATCH   8
#define NPTS    262144
#define PTSB    64
#define BLOCK   256

typedef __attribute__((ext_vector_type(8))) short sh8;
typedef __attribute__((ext_vector_type(4))) float f32x4;
typedef __attribute__((ext_vector_type(4))) uint  u32x4;

struct CoefTab { float c[54]; };   // [s][yk] SH normalization, host-computed

__device__ __forceinline__ ushort f2bf(float f) {   // round-to-nearest-even
    union { float f; uint u; } v; v.f = f;
    uint r = v.u + 0x7fffu + ((v.u >> 16) & 1u);
    return (ushort)(r >> 16);
}

// ---------------------------------------------------------------------------
// Prep (identical to proven version).
// ---------------------------------------------------------------------------
__global__ void sinr_prep(const float* __restrict__ a,
                          const float* __restrict__ Wcode,
                          const float* __restrict__ bcode,
                          const float* __restrict__ bfwd,
                          const float* __restrict__ Wftr,
                          const float* __restrict__ bftr,
                          const float* __restrict__ Wfwd,
                          CoefTab ct,
                          float* __restrict__ cterm,
                          ushort* __restrict__ wfB,
                          ushort* __restrict__ gwB) {
    int blk = blockIdx.x, tid = threadIdx.x;
    if (blk < DEPTH * BATCH) {
        if (tid < HIDDEN) {
            int i = blk / BATCH, b = blk % BATCH, h = tid;
            const float* ar = a + b * CODE;
            const float* wr = Wcode + (i * HIDDEN + h) * CODE;
            float acc = bcode[i * HIDDEN + h] + bfwd[i * HIDDEN + h];
            for (int c = 0; c < CODE; c += 4) {
                float4 av = *(const float4*)(ar + c);
                float4 wv = *(const float4*)(wr + c);
                acc = fmaf(av.x, wv.x, acc);
                acc = fmaf(av.y, wv.y, acc);
                acc = fmaf(av.z, wv.z, acc);
                acc = fmaf(av.w, wv.w, acc);
            }
            cterm[(i * BATCH + b) * HIDDEN + h] = acc;
        }
    } else if (blk < DEPTH * BATCH + 192) {
        int e = (blk - DEPTH * BATCH) * BLOCK + tid;     // < 49152
        int j    = e & 7;
        int lane = (e >> 3) & 63;
        int t    = (e >> 9) & 1;
        int nt   = (e >> 10) & 7;
        int s    = e >> 13;                               // 0..5
        int g  = nt * 16 + (lane & 15);
        int kq = lane >> 4;
        float v = 0.0f;
        if (kq == 0 || kq == 2) {
            v = ct.c[s * 9 + j] * Wftr[(s * HIDDEN + g) * NFREQ + j];
        } else if (kq == 1) {
            if (j == 0 || j == 1)
                v = ct.c[s * 9 + 8] * Wftr[(s * HIDDEN + g) * NFREQ + 8];
            else if (j == 2)
                v = bftr[s * HIDDEN + g];
        }
        uint u = __float_as_uint(v);
        float rf = v - __uint_as_float(u & 0xFFFF0000u);
        wfB[e] = t ? f2bf(rf) : (ushort)(u >> 16);
    } else {
        int e = (blk - DEPTH * BATCH - 192) * BLOCK + tid;  // < 163840
        if (e < DEPTH * 4 * 8 * 2 * 512) {
            int j     = e & 7;
            int lane  = (e >> 3) & 63;
            int img   = (e >> 9) & 1;
            int nt    = (e >> 10) & 7;
            int kq    = (e >> 13) & 3;
            int layer = e >> 15;
            int g = nt * 16 + (lane & 15);
            int h = kq * 32 + (lane >> 4) * 8 + j;
            float v = Wfwd[(layer * HIDDEN + g) * HIDDEN + h];
            uint u = __float_as_uint(v);
            float rf = v - __uint_as_float(u & 0xFFFF0000u);
            gwB[e] = img ? f2bf(rf) : (ushort)(u >> 16);
        }
    }
}

// ---------------------------------------------------------------------------
// Main. vs the correctness-proven R3 kernel, two perf fixes (no math change):
//  * launch_bounds(256,3): R3's (256,4) forced a 128-reg unified cap, below
//    the kernel's ~148-reg live set -> ~60 dwords/thread scratch spills ->
//    590 MB/dispatch HBM traffic (FETCH 327 MB, WRITE 248 MB) -> 273 us.
//    Bound 3 (cap 170) removes spills; occupancy comes from ACTUAL usage.
//  * fphase(layer+1) moved after the kq-loop barrier: facc (32 regs) no
//    longer live across the 96-MFMA kq loop, cutting peak pressure to ~100
//    so actual allocation lands <=128 -> 4 blocks/CU via the 38.9 KB LDS.
//    Schedule-safe: ypk buffer (layer+1)&1 was published one iteration
//    earlier (>=3 barriers before this read); its next overwrite is the
//    ystore at iteration layer+1 phase 1, >=1 barrier after this read.
// LDS: zh 16K + zl 16K + ypk 6K (2-shift dbuf) + zrow = 38.9 KB.
// ---------------------------------------------------------------------------
__global__ __launch_bounds__(BLOCK, 3)
void sinr_main(const float* __restrict__ x,
               const ushort* __restrict__ wfB,
               const ushort* __restrict__ gwB,
               const float* __restrict__ cterm,
               const float* __restrict__ Wout,
               const float* __restrict__ boutp,
               float* __restrict__ out,
               float* __restrict__ out_x) {
    __shared__ __align__(16) ushort zh16[PTSB * HIDDEN];     // 16 KB
    __shared__ __align__(16) ushort zl16[PTSB * HIDDEN];     // 16 KB
    __shared__ __align__(16) ushort ypk[2 * 3 * PTSB * 8];   // 6 KB (dbuf)
    __shared__ __align__(16) ushort zrow[8];

    const int tid  = threadIdx.x;
    const int lane = tid & 63;
    const int w    = tid >> 6;
    const int l15  = lane & 15, lq = lane >> 4;
    const int p0   = blockIdx.x * PTSB;
    const int b    = p0 >> 15;

    if (tid < 2 * PTSB) out_x[p0 * 2 + tid] = x[p0 * 2 + tid];
    if (tid < 8) zrow[tid] = 0;

    // staged pre-packed shift (wave w owns shift: w==0->4, 1->5, 2->2, 3->3)
    sh8 pk0, pk1, pk2;

    // store one packed shift triple into ypk buffer `buf`
    auto ystore = [&](int buf, const sh8& k0, const sh8& k1, const sh8& k2) {
        int off = (buf * 3 * PTSB + lane) * 8;
        *(sh8*)&ypk[off]                = k0;
        *(sh8*)&ypk[off + PTSB * 8]     = k1;
        *(sh8*)&ypk[off + 2 * PTSB * 8] = k2;
    };

    // ---- harmonics: every wave computes the full proven P/trig table ------
    {
        float th = x[(p0 + lane) * 2 + 0];
        float ph = x[(p0 + lane) * 2 + 1];
        float c  = cosf(ph);
        float somx2 = sqrtf(fmaxf(1.0f - c * c, 0.0f));
        float s1, c1;
        sincosf(th, &s1, &c1);
        float ctab[5], stab[5];
        ctab[0] = 1.0f; stab[0] = 0.0f;
        ctab[1] = c1;   stab[1] = s1;
#pragma unroll
        for (int k = 2; k <= 4; ++k) {
            ctab[k] = ctab[k - 1] * c1 - stab[k - 1] * s1;
            stab[k] = stab[k - 1] * c1 + ctab[k - 1] * s1;
        }
        float P[5][6];
        float pmm = 1.0f;
#pragma unroll
        for (int am = 0; am <= 4; ++am) {
            if (am > 0) pmm *= -(2.0f * am - 1.0f) * somx2;
            float pm2 = pmm;
            float pm1 = c * (2.0f * am + 1.0f) * pmm;
            P[am][0] = pm2;
            P[am][1] = pm1;
#pragma unroll
            for (int s = 2; s < 6; ++s) {
                int l = am + s;
                float pl = ((2.0f * l - 1.0f) * c * pm1
                            - (float)(l + am - 1) * pm2) / (float)(l - am);
                P[am][s] = pl;
                pm2 = pm1;
                pm1 = pl;
            }
        }
        // verbatim proven pack loop, parameterized by the 5 P values
        auto mk = [&](float Pv0, float Pv1, float Pv2, float Pv3, float Pv4,
                      sh8& k0, sh8& k1, sh8& k2) {
            float Pv[5] = {Pv0, Pv1, Pv2, Pv3, Pv4};
            ushort yh[9], yl[9];
#pragma unroll
            for (int mm = -4; mm <= 4; ++mm) {
                int am = mm < 0 ? -mm : mm;
                float trig = (mm > 0) ? ctab[am] : ((mm < 0) ? stab[am] : 1.0f);
                float yv = Pv[am] * trig;
                uint u = __float_as_uint(yv);
                yh[mm + 4] = (ushort)(u >> 16);
                float rf = yv - __uint_as_float(u & 0xFFFF0000u);
                yl[mm + 4] = (ushort)(__float_as_uint(rf) >> 16);
            }
#pragma unroll
            for (int j = 0; j < 8; ++j) { k0[j] = (short)yh[j]; k2[j] = (short)yl[j]; }
            k1[0] = (short)yh[8]; k1[1] = (short)yl[8]; k1[2] = (short)0x3F80;
            k1[3] = 0; k1[4] = 0; k1[5] = 0; k1[6] = 0; k1[7] = 0;
        };
        sh8 t0, t1, t2;
        if (w == 0) {
            mk(P[0][0], P[1][0], P[2][0], P[3][0], P[4][0], t0, t1, t2);
            ystore(0, t0, t1, t2);
            mk(P[0][4], P[1][4], P[2][4], P[3][4], P[4][4], pk0, pk1, pk2);
        } else if (w == 1) {
            mk(P[0][1], P[1][1], P[2][1], P[3][1], P[4][1], t0, t1, t2);
            ystore(1, t0, t1, t2);
            mk(P[0][5], P[1][5], P[2][5], P[3][5], P[4][5], pk0, pk1, pk2);
        } else if (w == 2) {
            mk(P[0][2], P[1][2], P[2][2], P[3][2], P[4][2], pk0, pk1, pk2);
        } else {
            mk(P[0][3], P[1][3], P[2][3], P[3][3], P[4][3], pk0, pk1, pk2);
        }
    }
    __syncthreads();

    // z store: row = mt*16+lq*4+r, col h = (w*2+nt)*16+l15; split-bf16 trunc
    // (verbatim proven version)
    auto zstore = [&](int mt, int nt, int r, float val) {
        int row = mt * 16 + lq * 4 + r;
        int hh  = (w * 2 + nt) * 16 + l15;
        int idx = row * HIDDEN + ((((hh >> 3) ^ (row & 15))) << 3) + (hh & 7);
        uint u = __float_as_uint(val);
        zh16[idx] = (ushort)(u >> 16);
        float rf = val - __uint_as_float(u & 0xFFFF0000u);
        zl16[idx] = (ushort)(__float_as_uint(rf) >> 16);
    };

    // F phase for shift s -> facc[4][2]; reads ypk buffer (s&1)
    auto fphase = [&](int s, f32x4 (*facc)[2]) {
        sh8 wb1[2], wb2[2];
#pragma unroll
        for (int nt = 0; nt < 2; ++nt) {
            const ushort* wp = wfB + s * 8192 + (w * 2 + nt) * 1024 + lane * 8;
            wb1[nt] = *(const sh8*)wp;
            wb2[nt] = *(const sh8*)(wp + 512);
        }
#pragma unroll
        for (int mt = 0; mt < 4; ++mt) {
            const ushort* ya = (lq < 3)
                ? &ypk[(((s & 1) * 3 + lq) * PTSB + mt * 16 + l15) * 8]
                : &zrow[0];
            sh8 yf = *(const sh8*)ya;
#pragma unroll
            for (int nt = 0; nt < 2; ++nt) {
                f32x4 t = (f32x4){0.f, 0.f, 0.f, 0.f};
                t = __builtin_amdgcn_mfma_f32_16x16x32_bf16(yf, wb1[nt], t, 0, 0, 0);
                t = __builtin_amdgcn_mfma_f32_16x16x32_bf16(yf, wb2[nt], t, 0, 0, 0);
                facc[mt][nt] = t;
            }
        }
    };

    // ---- z init: z0 = F(sft=0) ---------------------------------------------
    {
        f32x4 f0[4][2];
        fphase(0, f0);
#pragma unroll
        for (int mt = 0; mt < 4; ++mt)
#pragma unroll
            for (int nt = 0; nt < 2; ++nt)
#pragma unroll
                for (int r = 0; r < 4; ++r)
                    zstore(mt, nt, r, f0[mt][nt][r]);
    }
    __syncthreads();

    // ---- 5 layers (2 barriers/layer) ---------------------------------------
    for (int layer = 0; layer < DEPTH; ++layer) {
        // publish shift layer+2 (pre-packed regs) into buffer (layer+2)&1.
        // That buffer's last reader was fphase(layer) in the previous
        // iteration's phase 2, behind that iteration's second barrier.
        if (layer < DEPTH - 1 && w == ((layer + 2) & 3))
            ystore((layer + 2) & 1, pk0, pk1, pk2);

        float ctv[2];
#pragma unroll
        for (int nt = 0; nt < 2; ++nt)
            ctv[nt] = cterm[(layer * BATCH + b) * HIDDEN + (w * 2 + nt) * 16 + l15];

        f32x4 acc[4][2];
#pragma unroll
        for (int mt = 0; mt < 4; ++mt)
#pragma unroll
            for (int nt = 0; nt < 2; ++nt)
                acc[mt][nt] = (f32x4){0.f, 0.f, 0.f, 0.f};

#pragma unroll
        for (int kq = 0; kq < 4; ++kq) {
            const ushort* gp = gwB + (layer * 4 + kq) * 8192 + lane * 8;
            sh8 bh0 = *(const sh8*)(gp + (w * 2 + 0) * 1024);
            sh8 bl0 = *(const sh8*)(gp + (w * 2 + 0) * 1024 + 512);
            sh8 bh1 = *(const sh8*)(gp + (w * 2 + 1) * 1024);
            sh8 bl1 = *(const sh8*)(gp + (w * 2 + 1) * 1024 + 512);
#pragma unroll
            for (int mt = 0; mt < 4; ++mt) {
                int row  = mt * 16 + l15;
                int base = row * HIDDEN + (((kq * 4 + lq) ^ l15) << 3);
                sh8 ah = *(const sh8*)&zh16[base];
                sh8 al = *(const sh8*)&zl16[base];
                acc[mt][0] = __builtin_amdgcn_mfma_f32_16x16x32_bf16(ah, bh0, acc[mt][0], 0, 0, 0);
                acc[mt][0] = __builtin_amdgcn_mfma_f32_16x16x32_bf16(al, bh0, acc[mt][0], 0, 0, 0);
                acc[mt][0] = __builtin_amdgcn_mfma_f32_16x16x32_bf16(ah, bl0, acc[mt][0], 0, 0, 0);
                acc[mt][1] = __builtin_amdgcn_mfma_f32_16x16x32_bf16(ah, bh1, acc[mt][1], 0, 0, 0);
                acc[mt][1] = __builtin_amdgcn_mfma_f32_16x16x32_bf16(al, bh1, acc[mt][1], 0, 0, 0);
                acc[mt][1] = __builtin_amdgcn_mfma_f32_16x16x32_bf16(ah, bl1, acc[mt][1], 0, 0, 0);
            }
        }
        __syncthreads();   // all z reads complete before overwrite

        // F phase here (not before the kq loop): ypk slot for shift layer+1
        // is static since the previous iteration; facc stays live only
        // through the epilogue instead of across 96 MFMAs.
        f32x4 facc[4][2];
        fphase(layer + 1, facc);

        // epilogue: z_next = (acc + ct) * F
#pragma unroll
        for (int mt = 0; mt < 4; ++mt)
#pragma unroll
            for (int nt = 0; nt < 2; ++nt)
#pragma unroll
                for (int r = 0; r < 4; ++r)
                    zstore(mt, nt, r, (acc[mt][nt][r] + ctv[nt]) * facc[mt][nt][r]);
        __syncthreads();   // writes visible before next layer's reads
    }

    // ---- final: out[p] = (zh+zl) · Wout + bout (psum overlays dead ypk) ----
    float* psum = (float*)ypk;
    {
        int p = lane, qd = w;
        float accf = 0.0f;
#pragma unroll
        for (int cc = 0; cc < 4; ++cc) {
            int chunk = qd * 4 + cc;
            int base  = p * HIDDEN + ((chunk ^ (p & 15)) << 3);
            u32x4 hv = *(const u32x4*)&zh16[base];
            u32x4 lv = *(const u32x4*)&zl16[base];
            uint uh[4] = {hv.x, hv.y, hv.z, hv.w};
            uint ul[4] = {lv.x, lv.y, lv.z, lv.w};
            const float* wp = Wout + chunk * 8;
#pragma unroll
            for (int q2 = 0; q2 < 4; ++q2) {
                float a0 = __uint_as_float(uh[q2] << 16)
                         + __uint_as_float(ul[q2] << 16);
                float a1 = __uint_as_float(uh[q2] & 0xFFFF0000u)
                         + __uint_as_float(ul[q2] & 0xFFFF0000u);
                accf = fmaf(a0, wp[q2 * 2], accf);
                accf = fmaf(a1, wp[q2 * 2 + 1], accf);
            }
        }
        psum[qd * 64 + p] = accf;
    }
    __syncthreads();
    if (tid < PTSB) {
        out[p0 + tid] = boutp[0] + psum[tid] + psum[64 + tid]
                                 + psum[128 + tid] + psum[192 + tid];
    }
}

// ---------------------------------------------------------------------------
extern "C" void kernel_launch(void* const* d_in, const int* in_sizes, int n_in,
                              void* d_out, int out_size, void* d_ws, size_t ws_size,
                              hipStream_t stream) {
    (void)in_sizes; (void)n_in; (void)out_size; (void)ws_size;
    const float* x     = (const float*)d_in[0];
    const float* a     = (const float*)d_in[1];
    const float* Wftr  = (const float*)d_in[2];
    const float* bftr  = (const float*)d_in[3];
    const float* Wfwd  = (const float*)d_in[4];
    const float* bfwd  = (const float*)d_in[5];
    const float* Wcode = (const float*)d_in[6];
    const float* bcode = (const float*)d_in[7];
    const float* Wout  = (const float*)d_in[8];
    const float* bout  = (const float*)d_in[9];

    float* out   = (float*)d_out;                    // [B*N]
    float* out_x = out + NPTS;                       // [B*N*2]
    float*  cterm = (float*)d_ws;                    // 5120 floats
    ushort* wfB = (ushort*)(cterm + DEPTH * BATCH * HIDDEN);  // 49152 ushorts
    ushort* gwB = wfB + 49152;                                // 163840 ushorts

    // SH normalization coefficients on host (deterministic per call)
    CoefTab ct;
    for (int s = 0; s < 6; ++s)
        for (int yk = 0; yk < 9; ++yk) {
            int mm = yk - 4, am = mm < 0 ? -mm : mm, l = am + s;
            double ratio = 1.0;
            for (int q = l - am + 1; q <= l + am; ++q) ratio *= (double)q;
            double norm = sqrt((2.0 * l + 1.0) / (4.0 * M_PI * ratio));
            double cf = (mm == 0) ? norm : ((am & 1) ? -1.0 : 1.0) * sqrt(2.0) * norm;
            ct.c[s * 9 + yk] = (float)cf;
        }

    int nprep = DEPTH * BATCH + 192 + 640;
    sinr_prep<<<nprep, BLOCK, 0, stream>>>(a, Wcode, bcode, bfwd, Wftr, bftr,
                                           Wfwd, ct, cterm, wfB, gwB);
    sinr_main<<<NPTS / PTSB, BLOCK, 0, stream>>>(
        x, wfB, gwB, cterm, Wout, bout, out, out_x);
}

// Round 5
// 219.152 us; speedup vs baseline: 1.5150x; 1.0023x over previous
//
#include <hip/hip_runtime.h>
#include <math.h>

#define DEPTH   5
#define HIDDEN  128
#define CODE    400
#define NFREQ   9
#define BATCH   8
#define NPTS    262144
#define PTSB    64
#define BLOCK   256

typedef __attribute__((ext_vector_type(8))) short sh8;
typedef __attribute__((ext_vector_type(4))) float f32x4;
typedef __attribute__((ext_vector_type(4))) uint  u32x4;

struct CoefTab { float c[54]; };   // [s][yk] SH normalization, host-computed

__device__ __forceinline__ ushort f2bf(float f) {   // round-to-nearest-even
    union { float f; uint u; } v; v.f = f;
    uint r = v.u + 0x7fffu + ((v.u >> 16) & 1u);
    return (ushort)(r >> 16);
}

// ---------------------------------------------------------------------------
// Prep (identical to proven version).
// ---------------------------------------------------------------------------
__global__ void sinr_prep(const float* __restrict__ a,
                          const float* __restrict__ Wcode,
                          const float* __restrict__ bcode,
                          const float* __restrict__ bfwd,
                          const float* __restrict__ Wftr,
                          const float* __restrict__ bftr,
                          const float* __restrict__ Wfwd,
                          CoefTab ct,
                          float* __restrict__ cterm,
                          ushort* __restrict__ wfB,
                          ushort* __restrict__ gwB) {
    int blk = blockIdx.x, tid = threadIdx.x;
    if (blk < DEPTH * BATCH) {
        if (tid < HIDDEN) {
            int i = blk / BATCH, b = blk % BATCH, h = tid;
            const float* ar = a + b * CODE;
            const float* wr = Wcode + (i * HIDDEN + h) * CODE;
            float acc = bcode[i * HIDDEN + h] + bfwd[i * HIDDEN + h];
            for (int c = 0; c < CODE; c += 4) {
                float4 av = *(const float4*)(ar + c);
                float4 wv = *(const float4*)(wr + c);
                acc = fmaf(av.x, wv.x, acc);
                acc = fmaf(av.y, wv.y, acc);
                acc = fmaf(av.z, wv.z, acc);
                acc = fmaf(av.w, wv.w, acc);
            }
            cterm[(i * BATCH + b) * HIDDEN + h] = acc;
        }
    } else if (blk < DEPTH * BATCH + 192) {
        int e = (blk - DEPTH * BATCH) * BLOCK + tid;     // < 49152
        int j    = e & 7;
        int lane = (e >> 3) & 63;
        int t    = (e >> 9) & 1;
        int nt   = (e >> 10) & 7;
        int s    = e >> 13;                               // 0..5
        int g  = nt * 16 + (lane & 15);
        int kq = lane >> 4;
        float v = 0.0f;
        if (kq == 0 || kq == 2) {
            v = ct.c[s * 9 + j] * Wftr[(s * HIDDEN + g) * NFREQ + j];
        } else if (kq == 1) {
            if (j == 0 || j == 1)
                v = ct.c[s * 9 + 8] * Wftr[(s * HIDDEN + g) * NFREQ + 8];
            else if (j == 2)
                v = bftr[s * HIDDEN + g];
        }
        uint u = __float_as_uint(v);
        float rf = v - __uint_as_float(u & 0xFFFF0000u);
        wfB[e] = t ? f2bf(rf) : (ushort)(u >> 16);
    } else {
        int e = (blk - DEPTH * BATCH - 192) * BLOCK + tid;  // < 163840
        if (e < DEPTH * 4 * 8 * 2 * 512) {
            int j     = e & 7;
            int lane  = (e >> 3) & 63;
            int img   = (e >> 9) & 1;
            int nt    = (e >> 10) & 7;
            int kq    = (e >> 13) & 3;
            int layer = e >> 15;
            int g = nt * 16 + (lane & 15);
            int h = kq * 32 + (lane >> 4) * 8 + j;
            float v = Wfwd[(layer * HIDDEN + g) * HIDDEN + h];
            uint u = __float_as_uint(v);
            float rf = v - __uint_as_float(u & 0xFFFF0000u);
            gwB[e] = img ? f2bf(rf) : (ushort)(u >> 16);
        }
    }
}

// ---------------------------------------------------------------------------
// Main. vs R4 (159 us proven): ONE change — the post-kq F phase is fused
// per-mt into the epilogue. R4 materialized facc[4][2] (32 regs) fully while
// acc[4][2] (32 regs) was also live -> ~148 unified regs -> 3 waves/SIMD
// (Occupancy 30%). Fusion keeps only facc_mt[2] (8 regs) live per mt, peak
// ~115-124 regs -> 4 waves/SIMD with the 38.9 KB LDS (4 blocks/CU).
// Same MFMA pairs, same (acc+ct)*F order per element -> identical bits.
// ypk double-buffer schedule untouched (fphase stays in the same
// inter-barrier phase as R4).
// ---------------------------------------------------------------------------
__global__ __launch_bounds__(BLOCK, 3)
void sinr_main(const float* __restrict__ x,
               const ushort* __restrict__ wfB,
               const ushort* __restrict__ gwB,
               const float* __restrict__ cterm,
               const float* __restrict__ Wout,
               const float* __restrict__ boutp,
               float* __restrict__ out,
               float* __restrict__ out_x) {
    __shared__ __align__(16) ushort zh16[PTSB * HIDDEN];     // 16 KB
    __shared__ __align__(16) ushort zl16[PTSB * HIDDEN];     // 16 KB
    __shared__ __align__(16) ushort ypk[2 * 3 * PTSB * 8];   // 6 KB (dbuf)
    __shared__ __align__(16) ushort zrow[8];

    const int tid  = threadIdx.x;
    const int lane = tid & 63;
    const int w    = tid >> 6;
    const int l15  = lane & 15, lq = lane >> 4;
    const int p0   = blockIdx.x * PTSB;
    const int b    = p0 >> 15;

    if (tid < 2 * PTSB) out_x[p0 * 2 + tid] = x[p0 * 2 + tid];
    if (tid < 8) zrow[tid] = 0;

    // staged pre-packed shift (wave w owns shift: w==0->4, 1->5, 2->2, 3->3)
    sh8 pk0, pk1, pk2;

    // store one packed shift triple into ypk buffer `buf`
    auto ystore = [&](int buf, const sh8& k0, const sh8& k1, const sh8& k2) {
        int off = (buf * 3 * PTSB + lane) * 8;
        *(sh8*)&ypk[off]                = k0;
        *(sh8*)&ypk[off + PTSB * 8]     = k1;
        *(sh8*)&ypk[off + 2 * PTSB * 8] = k2;
    };

    // ---- harmonics: every wave computes the full proven P/trig table ------
    {
        float th = x[(p0 + lane) * 2 + 0];
        float ph = x[(p0 + lane) * 2 + 1];
        float c  = cosf(ph);
        float somx2 = sqrtf(fmaxf(1.0f - c * c, 0.0f));
        float s1, c1;
        sincosf(th, &s1, &c1);
        float ctab[5], stab[5];
        ctab[0] = 1.0f; stab[0] = 0.0f;
        ctab[1] = c1;   stab[1] = s1;
#pragma unroll
        for (int k = 2; k <= 4; ++k) {
            ctab[k] = ctab[k - 1] * c1 - stab[k - 1] * s1;
            stab[k] = stab[k - 1] * c1 + ctab[k - 1] * s1;
        }
        float P[5][6];
        float pmm = 1.0f;
#pragma unroll
        for (int am = 0; am <= 4; ++am) {
            if (am > 0) pmm *= -(2.0f * am - 1.0f) * somx2;
            float pm2 = pmm;
            float pm1 = c * (2.0f * am + 1.0f) * pmm;
            P[am][0] = pm2;
            P[am][1] = pm1;
#pragma unroll
            for (int s = 2; s < 6; ++s) {
                int l = am + s;
                float pl = ((2.0f * l - 1.0f) * c * pm1
                            - (float)(l + am - 1) * pm2) / (float)(l - am);
                P[am][s] = pl;
                pm2 = pm1;
                pm1 = pl;
            }
        }
        // verbatim proven pack loop, parameterized by the 5 P values
        auto mk = [&](float Pv0, float Pv1, float Pv2, float Pv3, float Pv4,
                      sh8& k0, sh8& k1, sh8& k2) {
            float Pv[5] = {Pv0, Pv1, Pv2, Pv3, Pv4};
            ushort yh[9], yl[9];
#pragma unroll
            for (int mm = -4; mm <= 4; ++mm) {
                int am = mm < 0 ? -mm : mm;
                float trig = (mm > 0) ? ctab[am] : ((mm < 0) ? stab[am] : 1.0f);
                float yv = Pv[am] * trig;
                uint u = __float_as_uint(yv);
                yh[mm + 4] = (ushort)(u >> 16);
                float rf = yv - __uint_as_float(u & 0xFFFF0000u);
                yl[mm + 4] = (ushort)(__float_as_uint(rf) >> 16);
            }
#pragma unroll
            for (int j = 0; j < 8; ++j) { k0[j] = (short)yh[j]; k2[j] = (short)yl[j]; }
            k1[0] = (short)yh[8]; k1[1] = (short)yl[8]; k1[2] = (short)0x3F80;
            k1[3] = 0; k1[4] = 0; k1[5] = 0; k1[6] = 0; k1[7] = 0;
        };
        sh8 t0, t1, t2;
        if (w == 0) {
            mk(P[0][0], P[1][0], P[2][0], P[3][0], P[4][0], t0, t1, t2);
            ystore(0, t0, t1, t2);
            mk(P[0][4], P[1][4], P[2][4], P[3][4], P[4][4], pk0, pk1, pk2);
        } else if (w == 1) {
            mk(P[0][1], P[1][1], P[2][1], P[3][1], P[4][1], t0, t1, t2);
            ystore(1, t0, t1, t2);
            mk(P[0][5], P[1][5], P[2][5], P[3][5], P[4][5], pk0, pk1, pk2);
        } else if (w == 2) {
            mk(P[0][2], P[1][2], P[2][2], P[3][2], P[4][2], pk0, pk1, pk2);
        } else {
            mk(P[0][3], P[1][3], P[2][3], P[3][3], P[4][3], pk0, pk1, pk2);
        }
    }
    __syncthreads();

    // z store: row = mt*16+lq*4+r, col h = (w*2+nt)*16+l15; split-bf16 trunc
    // (verbatim proven version)
    auto zstore = [&](int mt, int nt, int r, float val) {
        int row = mt * 16 + lq * 4 + r;
        int hh  = (w * 2 + nt) * 16 + l15;
        int idx = row * HIDDEN + ((((hh >> 3) ^ (row & 15))) << 3) + (hh & 7);
        uint u = __float_as_uint(val);
        zh16[idx] = (ushort)(u >> 16);
        float rf = val - __uint_as_float(u & 0xFFFF0000u);
        zl16[idx] = (ushort)(__float_as_uint(rf) >> 16);
    };

    // ---- z init: z0 = F(sft=0), fused per-mt -------------------------------
    {
        sh8 wb1[2], wb2[2];
#pragma unroll
        for (int nt = 0; nt < 2; ++nt) {
            const ushort* wp = wfB + 0 * 8192 + (w * 2 + nt) * 1024 + lane * 8;
            wb1[nt] = *(const sh8*)wp;
            wb2[nt] = *(const sh8*)(wp + 512);
        }
#pragma unroll
        for (int mt = 0; mt < 4; ++mt) {
            const ushort* ya = (lq < 3)
                ? &ypk[((0 * 3 + lq) * PTSB + mt * 16 + l15) * 8]
                : &zrow[0];
            sh8 yf = *(const sh8*)ya;
#pragma unroll
            for (int nt = 0; nt < 2; ++nt) {
                f32x4 t = (f32x4){0.f, 0.f, 0.f, 0.f};
                t = __builtin_amdgcn_mfma_f32_16x16x32_bf16(yf, wb1[nt], t, 0, 0, 0);
                t = __builtin_amdgcn_mfma_f32_16x16x32_bf16(yf, wb2[nt], t, 0, 0, 0);
#pragma unroll
                for (int r = 0; r < 4; ++r)
                    zstore(mt, nt, r, t[r]);
            }
        }
    }
    __syncthreads();

    // ---- 5 layers (2 barriers/layer) ---------------------------------------
    for (int layer = 0; layer < DEPTH; ++layer) {
        // publish shift layer+2 (pre-packed regs) into buffer (layer+2)&1.
        // That buffer's last reader was the fused F phase of iteration
        // layer-1 (shift layer), behind that iteration's second barrier.
        if (layer < DEPTH - 1 && w == ((layer + 2) & 3))
            ystore((layer + 2) & 1, pk0, pk1, pk2);

        float ctv[2];
#pragma unroll
        for (int nt = 0; nt < 2; ++nt)
            ctv[nt] = cterm[(layer * BATCH + b) * HIDDEN + (w * 2 + nt) * 16 + l15];

        f32x4 acc[4][2];
#pragma unroll
        for (int mt = 0; mt < 4; ++mt)
#pragma unroll
            for (int nt = 0; nt < 2; ++nt)
                acc[mt][nt] = (f32x4){0.f, 0.f, 0.f, 0.f};

#pragma unroll
        for (int kq = 0; kq < 4; ++kq) {
            const ushort* gp = gwB + (layer * 4 + kq) * 8192 + lane * 8;
            sh8 bh0 = *(const sh8*)(gp + (w * 2 + 0) * 1024);
            sh8 bl0 = *(const sh8*)(gp + (w * 2 + 0) * 1024 + 512);
            sh8 bh1 = *(const sh8*)(gp + (w * 2 + 1) * 1024);
            sh8 bl1 = *(const sh8*)(gp + (w * 2 + 1) * 1024 + 512);
#pragma unroll
            for (int mt = 0; mt < 4; ++mt) {
                int row  = mt * 16 + l15;
                int base = row * HIDDEN + (((kq * 4 + lq) ^ l15) << 3);
                sh8 ah = *(const sh8*)&zh16[base];
                sh8 al = *(const sh8*)&zl16[base];
                acc[mt][0] = __builtin_amdgcn_mfma_f32_16x16x32_bf16(ah, bh0, acc[mt][0], 0, 0, 0);
                acc[mt][0] = __builtin_amdgcn_mfma_f32_16x16x32_bf16(al, bh0, acc[mt][0], 0, 0, 0);
                acc[mt][0] = __builtin_amdgcn_mfma_f32_16x16x32_bf16(ah, bl0, acc[mt][0], 0, 0, 0);
                acc[mt][1] = __builtin_amdgcn_mfma_f32_16x16x32_bf16(ah, bh1, acc[mt][1], 0, 0, 0);
                acc[mt][1] = __builtin_amdgcn_mfma_f32_16x16x32_bf16(al, bh1, acc[mt][1], 0, 0, 0);
                acc[mt][1] = __builtin_amdgcn_mfma_f32_16x16x32_bf16(ah, bl1, acc[mt][1], 0, 0, 0);
            }
        }
        __syncthreads();   // all z reads complete before overwrite

        // fused F phase + epilogue, per mt: z_next = (acc + ct) * F.
        // Same ypk slot timing as R4's fphase here; facc live set is 8 regs
        // (one mt) instead of 32, so acc+facc never peak together.
        {
            sh8 wb1[2], wb2[2];
#pragma unroll
            for (int nt = 0; nt < 2; ++nt) {
                const ushort* wp = wfB + (layer + 1) * 8192 + (w * 2 + nt) * 1024 + lane * 8;
                wb1[nt] = *(const sh8*)wp;
                wb2[nt] = *(const sh8*)(wp + 512);
            }
#pragma unroll
            for (int mt = 0; mt < 4; ++mt) {
                const ushort* ya = (lq < 3)
                    ? &ypk[((((layer + 1) & 1) * 3 + lq) * PTSB + mt * 16 + l15) * 8]
                    : &zrow[0];
                sh8 yf = *(const sh8*)ya;
#pragma unroll
                for (int nt = 0; nt < 2; ++nt) {
                    f32x4 t = (f32x4){0.f, 0.f, 0.f, 0.f};
                    t = __builtin_amdgcn_mfma_f32_16x16x32_bf16(yf, wb1[nt], t, 0, 0, 0);
                    t = __builtin_amdgcn_mfma_f32_16x16x32_bf16(yf, wb2[nt], t, 0, 0, 0);
#pragma unroll
                    for (int r = 0; r < 4; ++r)
                        zstore(mt, nt, r, (acc[mt][nt][r] + ctv[nt]) * t[r]);
                }
            }
        }
        __syncthreads();   // writes visible before next layer's reads
    }

    // ---- final: out[p] = (zh+zl) · Wout + bout (psum overlays dead ypk) ----
    float* psum = (float*)ypk;
    {
        int p = lane, qd = w;
        float accf = 0.0f;
#pragma unroll
        for (int cc = 0; cc < 4; ++cc) {
            int chunk = qd * 4 + cc;
            int base  = p * HIDDEN + ((chunk ^ (p & 15)) << 3);
            u32x4 hv = *(const u32x4*)&zh16[base];
            u32x4 lv = *(const u32x4*)&zl16[base];
            uint uh[4] = {hv.x, hv.y, hv.z, hv.w};
            uint ul[4] = {lv.x, lv.y, lv.z, lv.w};
            const float* wp = Wout + chunk * 8;
#pragma unroll
            for (int q2 = 0; q2 < 4; ++q2) {
                float a0 = __uint_as_float(uh[q2] << 16)
                         + __uint_as_float(ul[q2] << 16);
                float a1 = __uint_as_float(uh[q2] & 0xFFFF0000u)
                         + __uint_as_float(ul[q2] & 0xFFFF0000u);
                accf = fmaf(a0, wp[q2 * 2], accf);
                accf = fmaf(a1, wp[q2 * 2 + 1], accf);
            }
        }
        psum[qd * 64 + p] = accf;
    }
    __syncthreads();
    if (tid < PTSB) {
        out[p0 + tid] = boutp[0] + psum[tid] + psum[64 + tid]
                                 + psum[128 + tid] + psum[192 + tid];
    }
}

// ---------------------------------------------------------------------------
extern "C" void kernel_launch(void* const* d_in, const int* in_sizes, int n_in,
                              void* d_out, int out_size, void* d_ws, size_t ws_size,
                              hipStream_t stream) {
    (void)in_sizes; (void)n_in; (void)out_size; (void)ws_size;
    const float* x     = (const float*)d_in[0];
    const float* a     = (const float*)d_in[1];
    const float* Wftr  = (const float*)d_in[2];
    const float* bftr  = (const float*)d_in[3];
    const float* Wfwd  = (const float*)d_in[4];
    const float* bfwd  = (const float*)d_in[5];
    const float* Wcode = (const float*)d_in[6];
    const float* bcode = (const float*)d_in[7];
    const float* Wout  = (const float*)d_in[8];
    const float* bout  = (const float*)d_in[9];

    float* out   = (float*)d_out;                    // [B*N]
    float* out_x = out + NPTS;                       // [B*N*2]
    float*  cterm = (float*)d_ws;                    // 5120 floats
    ushort* wfB = (ushort*)(cterm + DEPTH * BATCH * HIDDEN);  // 49152 ushorts
    ushort* gwB = wfB + 49152;                                // 163840 ushorts

    // SH normalization coefficients on host (deterministic per call)
    CoefTab ct;
    for (int s = 0; s < 6; ++s)
        for (int yk = 0; yk < 9; ++yk) {
            int mm = yk - 4, am = mm < 0 ? -mm : mm, l = am + s;
            double ratio = 1.0;
            for (int q = l - am + 1; q <= l + am; ++q) ratio *= (double)q;
            double norm = sqrt((2.0 * l + 1.0) / (4.0 * M_PI * ratio));
            double cf = (mm == 0) ? norm : ((am & 1) ? -1.0 : 1.0) * sqrt(2.0) * norm;
            ct.c[s * 9 + yk] = (float)cf;
        }

    int nprep = DEPTH * BATCH + 192 + 640;
    sinr_prep<<<nprep, BLOCK, 0, stream>>>(a, Wcode, bcode, bfwd, Wftr, bftr,
                                           Wfwd, ct, cterm, wfB, gwB);
    sinr_main<<<NPTS / PTSB, BLOCK, 0, stream>>>(
        x, wfB, gwB, cterm, Wout, bout, out, out_x);
}

// Round 6
// 196.376 us; speedup vs baseline: 1.6907x; 1.1160x over previous
//
#include <hip/hip_runtime.h>
#include <math.h>

#define DEPTH   5
#define HIDDEN  128
#define CODE    400
#define NFREQ   9
#define BATCH   8
#define NPTS    262144
#define PTSB    64
#define BLOCK   256

typedef __attribute__((ext_vector_type(8))) short sh8;
typedef __attribute__((ext_vector_type(4))) float f32x4;
typedef __attribute__((ext_vector_type(4))) uint  u32x4;

struct CoefTab { float c[54]; };   // [s][yk] SH normalization, host-computed

__device__ __forceinline__ ushort f2bf(float f) {   // round-to-nearest-even
    union { float f; uint u; } v; v.f = f;
    uint r = v.u + 0x7fffu + ((v.u >> 16) & 1u);
    return (ushort)(r >> 16);
}

// ---------------------------------------------------------------------------
// Prep. vs R5: gwB is now a SINGLE round-to-nearest bf16 image of Wfwd
// (no lo image): [layer][kq][nt][lane][j] = 5*4*8*512 = 81920 ushorts.
// wfB (filter, split) and cterm unchanged.
// ---------------------------------------------------------------------------
__global__ void sinr_prep(const float* __restrict__ a,
                          const float* __restrict__ Wcode,
                          const float* __restrict__ bcode,
                          const float* __restrict__ bfwd,
                          const float* __restrict__ Wftr,
                          const float* __restrict__ bftr,
                          const float* __restrict__ Wfwd,
                          CoefTab ct,
                          float* __restrict__ cterm,
                          ushort* __restrict__ wfB,
                          ushort* __restrict__ gwB) {
    int blk = blockIdx.x, tid = threadIdx.x;
    if (blk < DEPTH * BATCH) {
        if (tid < HIDDEN) {
            int i = blk / BATCH, b = blk % BATCH, h = tid;
            const float* ar = a + b * CODE;
            const float* wr = Wcode + (i * HIDDEN + h) * CODE;
            float acc = bcode[i * HIDDEN + h] + bfwd[i * HIDDEN + h];
            for (int c = 0; c < CODE; c += 4) {
                float4 av = *(const float4*)(ar + c);
                float4 wv = *(const float4*)(wr + c);
                acc = fmaf(av.x, wv.x, acc);
                acc = fmaf(av.y, wv.y, acc);
                acc = fmaf(av.z, wv.z, acc);
                acc = fmaf(av.w, wv.w, acc);
            }
            cterm[(i * BATCH + b) * HIDDEN + h] = acc;
        }
    } else if (blk < DEPTH * BATCH + 192) {
        int e = (blk - DEPTH * BATCH) * BLOCK + tid;     // < 49152
        int j    = e & 7;
        int lane = (e >> 3) & 63;
        int t    = (e >> 9) & 1;
        int nt   = (e >> 10) & 7;
        int s    = e >> 13;                               // 0..5
        int g  = nt * 16 + (lane & 15);
        int kq = lane >> 4;
        float v = 0.0f;
        if (kq == 0 || kq == 2) {
            v = ct.c[s * 9 + j] * Wftr[(s * HIDDEN + g) * NFREQ + j];
        } else if (kq == 1) {
            if (j == 0 || j == 1)
                v = ct.c[s * 9 + 8] * Wftr[(s * HIDDEN + g) * NFREQ + 8];
            else if (j == 2)
                v = bftr[s * HIDDEN + g];
        }
        uint u = __float_as_uint(v);
        float rf = v - __uint_as_float(u & 0xFFFF0000u);
        wfB[e] = t ? f2bf(rf) : (ushort)(u >> 16);
    } else {
        int e = (blk - DEPTH * BATCH - 192) * BLOCK + tid;  // < 81920
        if (e < DEPTH * 4 * 8 * 512) {
            int j     = e & 7;
            int lane  = (e >> 3) & 63;
            int nt    = (e >> 9) & 7;
            int kq    = (e >> 12) & 3;
            int layer = e >> 14;
            int g = nt * 16 + (lane & 15);
            int h = kq * 32 + (lane >> 4) * 8 + j;
            gwB[e] = f2bf(Wfwd[(layer * HIDDEN + g) * HIDDEN + h]);
        }
    }
}

// ---------------------------------------------------------------------------
// Main. vs R5 (158 us proven): ONE change — Wfwd used as a single ROUNDED
// bf16 image. kq loop does 4 MFMAs per (kq,mt): ah*b0, al*b0, ah*b1, al*b1
// (was 6 with the ah*bl correction). Per-wave MFMA 576 -> 416 (-28%).
// z stays split bf16 (zh+zl); F filter stays split. Expected extra error
// ~2^-9 relative per layer from W rounding (threshold 0.02, was 0.00195).
// Everything else verbatim R5 (proven ypk dbuf schedule, fused F epilogue).
// ---------------------------------------------------------------------------
__global__ __launch_bounds__(BLOCK, 3)
void sinr_main(const float* __restrict__ x,
               const ushort* __restrict__ wfB,
               const ushort* __restrict__ gwB,
               const float* __restrict__ cterm,
               const float* __restrict__ Wout,
               const float* __restrict__ boutp,
               float* __restrict__ out,
               float* __restrict__ out_x) {
    __shared__ __align__(16) ushort zh16[PTSB * HIDDEN];     // 16 KB
    __shared__ __align__(16) ushort zl16[PTSB * HIDDEN];     // 16 KB
    __shared__ __align__(16) ushort ypk[2 * 3 * PTSB * 8];   // 6 KB (dbuf)
    __shared__ __align__(16) ushort zrow[8];

    const int tid  = threadIdx.x;
    const int lane = tid & 63;
    const int w    = tid >> 6;
    const int l15  = lane & 15, lq = lane >> 4;
    const int p0   = blockIdx.x * PTSB;
    const int b    = p0 >> 15;

    if (tid < 2 * PTSB) out_x[p0 * 2 + tid] = x[p0 * 2 + tid];
    if (tid < 8) zrow[tid] = 0;

    // staged pre-packed shift (wave w owns shift: w==0->4, 1->5, 2->2, 3->3)
    sh8 pk0, pk1, pk2;

    // store one packed shift triple into ypk buffer `buf`
    auto ystore = [&](int buf, const sh8& k0, const sh8& k1, const sh8& k2) {
        int off = (buf * 3 * PTSB + lane) * 8;
        *(sh8*)&ypk[off]                = k0;
        *(sh8*)&ypk[off + PTSB * 8]     = k1;
        *(sh8*)&ypk[off + 2 * PTSB * 8] = k2;
    };

    // ---- harmonics: every wave computes the full proven P/trig table ------
    {
        float th = x[(p0 + lane) * 2 + 0];
        float ph = x[(p0 + lane) * 2 + 1];
        float c  = cosf(ph);
        float somx2 = sqrtf(fmaxf(1.0f - c * c, 0.0f));
        float s1, c1;
        sincosf(th, &s1, &c1);
        float ctab[5], stab[5];
        ctab[0] = 1.0f; stab[0] = 0.0f;
        ctab[1] = c1;   stab[1] = s1;
#pragma unroll
        for (int k = 2; k <= 4; ++k) {
            ctab[k] = ctab[k - 1] * c1 - stab[k - 1] * s1;
            stab[k] = stab[k - 1] * c1 + ctab[k - 1] * s1;
        }
        float P[5][6];
        float pmm = 1.0f;
#pragma unroll
        for (int am = 0; am <= 4; ++am) {
            if (am > 0) pmm *= -(2.0f * am - 1.0f) * somx2;
            float pm2 = pmm;
            float pm1 = c * (2.0f * am + 1.0f) * pmm;
            P[am][0] = pm2;
            P[am][1] = pm1;
#pragma unroll
            for (int s = 2; s < 6; ++s) {
                int l = am + s;
                float pl = ((2.0f * l - 1.0f) * c * pm1
                            - (float)(l + am - 1) * pm2) / (float)(l - am);
                P[am][s] = pl;
                pm2 = pm1;
                pm1 = pl;
            }
        }
        // verbatim proven pack loop, parameterized by the 5 P values
        auto mk = [&](float Pv0, float Pv1, float Pv2, float Pv3, float Pv4,
                      sh8& k0, sh8& k1, sh8& k2) {
            float Pv[5] = {Pv0, Pv1, Pv2, Pv3, Pv4};
            ushort yh[9], yl[9];
#pragma unroll
            for (int mm = -4; mm <= 4; ++mm) {
                int am = mm < 0 ? -mm : mm;
                float trig = (mm > 0) ? ctab[am] : ((mm < 0) ? stab[am] : 1.0f);
                float yv = Pv[am] * trig;
                uint u = __float_as_uint(yv);
                yh[mm + 4] = (ushort)(u >> 16);
                float rf = yv - __uint_as_float(u & 0xFFFF0000u);
                yl[mm + 4] = (ushort)(__float_as_uint(rf) >> 16);
            }
#pragma unroll
            for (int j = 0; j < 8; ++j) { k0[j] = (short)yh[j]; k2[j] = (short)yl[j]; }
            k1[0] = (short)yh[8]; k1[1] = (short)yl[8]; k1[2] = (short)0x3F80;
            k1[3] = 0; k1[4] = 0; k1[5] = 0; k1[6] = 0; k1[7] = 0;
        };
        sh8 t0, t1, t2;
        if (w == 0) {
            mk(P[0][0], P[1][0], P[2][0], P[3][0], P[4][0], t0, t1, t2);
            ystore(0, t0, t1, t2);
            mk(P[0][4], P[1][4], P[2][4], P[3][4], P[4][4], pk0, pk1, pk2);
        } else if (w == 1) {
            mk(P[0][1], P[1][1], P[2][1], P[3][1], P[4][1], t0, t1, t2);
            ystore(1, t0, t1, t2);
            mk(P[0][5], P[1][5], P[2][5], P[3][5], P[4][5], pk0, pk1, pk2);
        } else if (w == 2) {
            mk(P[0][2], P[1][2], P[2][2], P[3][2], P[4][2], pk0, pk1, pk2);
        } else {
            mk(P[0][3], P[1][3], P[2][3], P[3][3], P[4][3], pk0, pk1, pk2);
        }
    }
    __syncthreads();

    // z store: row = mt*16+lq*4+r, col h = (w*2+nt)*16+l15; split-bf16 trunc
    // (verbatim proven version)
    auto zstore = [&](int mt, int nt, int r, float val) {
        int row = mt * 16 + lq * 4 + r;
        int hh  = (w * 2 + nt) * 16 + l15;
        int idx = row * HIDDEN + ((((hh >> 3) ^ (row & 15))) << 3) + (hh & 7);
        uint u = __float_as_uint(val);
        zh16[idx] = (ushort)(u >> 16);
        float rf = val - __uint_as_float(u & 0xFFFF0000u);
        zl16[idx] = (ushort)(__float_as_uint(rf) >> 16);
    };

    // ---- z init: z0 = F(sft=0), fused per-mt -------------------------------
    {
        sh8 wb1[2], wb2[2];
#pragma unroll
        for (int nt = 0; nt < 2; ++nt) {
            const ushort* wp = wfB + 0 * 8192 + (w * 2 + nt) * 1024 + lane * 8;
            wb1[nt] = *(const sh8*)wp;
            wb2[nt] = *(const sh8*)(wp + 512);
        }
#pragma unroll
        for (int mt = 0; mt < 4; ++mt) {
            const ushort* ya = (lq < 3)
                ? &ypk[((0 * 3 + lq) * PTSB + mt * 16 + l15) * 8]
                : &zrow[0];
            sh8 yf = *(const sh8*)ya;
#pragma unroll
            for (int nt = 0; nt < 2; ++nt) {
                f32x4 t = (f32x4){0.f, 0.f, 0.f, 0.f};
                t = __builtin_amdgcn_mfma_f32_16x16x32_bf16(yf, wb1[nt], t, 0, 0, 0);
                t = __builtin_amdgcn_mfma_f32_16x16x32_bf16(yf, wb2[nt], t, 0, 0, 0);
#pragma unroll
                for (int r = 0; r < 4; ++r)
                    zstore(mt, nt, r, t[r]);
            }
        }
    }
    __syncthreads();

    // ---- 5 layers (2 barriers/layer) ---------------------------------------
    for (int layer = 0; layer < DEPTH; ++layer) {
        // publish shift layer+2 (pre-packed regs) into buffer (layer+2)&1.
        // That buffer's last reader was the fused F phase of iteration
        // layer-1 (shift layer), behind that iteration's second barrier.
        if (layer < DEPTH - 1 && w == ((layer + 2) & 3))
            ystore((layer + 2) & 1, pk0, pk1, pk2);

        float ctv[2];
#pragma unroll
        for (int nt = 0; nt < 2; ++nt)
            ctv[nt] = cterm[(layer * BATCH + b) * HIDDEN + (w * 2 + nt) * 16 + l15];

        f32x4 acc[4][2];
#pragma unroll
        for (int mt = 0; mt < 4; ++mt)
#pragma unroll
            for (int nt = 0; nt < 2; ++nt)
                acc[mt][nt] = (f32x4){0.f, 0.f, 0.f, 0.f};

#pragma unroll
        for (int kq = 0; kq < 4; ++kq) {
            // single rounded-bf16 Wfwd image: [layer][kq][nt][lane][j]
            const ushort* gp = gwB + (layer * 4 + kq) * 4096 + lane * 8;
            sh8 bh0 = *(const sh8*)(gp + (w * 2 + 0) * 512);
            sh8 bh1 = *(const sh8*)(gp + (w * 2 + 1) * 512);
#pragma unroll
            for (int mt = 0; mt < 4; ++mt) {
                int row  = mt * 16 + l15;
                int base = row * HIDDEN + (((kq * 4 + lq) ^ l15) << 3);
                sh8 ah = *(const sh8*)&zh16[base];
                sh8 al = *(const sh8*)&zl16[base];
                acc[mt][0] = __builtin_amdgcn_mfma_f32_16x16x32_bf16(ah, bh0, acc[mt][0], 0, 0, 0);
                acc[mt][0] = __builtin_amdgcn_mfma_f32_16x16x32_bf16(al, bh0, acc[mt][0], 0, 0, 0);
                acc[mt][1] = __builtin_amdgcn_mfma_f32_16x16x32_bf16(ah, bh1, acc[mt][1], 0, 0, 0);
                acc[mt][1] = __builtin_amdgcn_mfma_f32_16x16x32_bf16(al, bh1, acc[mt][1], 0, 0, 0);
            }
        }
        __syncthreads();   // all z reads complete before overwrite

        // fused F phase + epilogue, per mt: z_next = (acc + ct) * F.
        {
            sh8 wb1[2], wb2[2];
#pragma unroll
            for (int nt = 0; nt < 2; ++nt) {
                const ushort* wp = wfB + (layer + 1) * 8192 + (w * 2 + nt) * 1024 + lane * 8;
                wb1[nt] = *(const sh8*)wp;
                wb2[nt] = *(const sh8*)(wp + 512);
            }
#pragma unroll
            for (int mt = 0; mt < 4; ++mt) {
                const ushort* ya = (lq < 3)
                    ? &ypk[((((layer + 1) & 1) * 3 + lq) * PTSB + mt * 16 + l15) * 8]
                    : &zrow[0];
                sh8 yf = *(const sh8*)ya;
#pragma unroll
                for (int nt = 0; nt < 2; ++nt) {
                    f32x4 t = (f32x4){0.f, 0.f, 0.f, 0.f};
                    t = __builtin_amdgcn_mfma_f32_16x16x32_bf16(yf, wb1[nt], t, 0, 0, 0);
                    t = __builtin_amdgcn_mfma_f32_16x16x32_bf16(yf, wb2[nt], t, 0, 0, 0);
#pragma unroll
                    for (int r = 0; r < 4; ++r)
                        zstore(mt, nt, r, (acc[mt][nt][r] + ctv[nt]) * t[r]);
                }
            }
        }
        __syncthreads();   // writes visible before next layer's reads
    }

    // ---- final: out[p] = (zh+zl) · Wout + bout (psum overlays dead ypk) ----
    float* psum = (float*)ypk;
    {
        int p = lane, qd = w;
        float accf = 0.0f;
#pragma unroll
        for (int cc = 0; cc < 4; ++cc) {
            int chunk = qd * 4 + cc;
            int base  = p * HIDDEN + ((chunk ^ (p & 15)) << 3);
            u32x4 hv = *(const u32x4*)&zh16[base];
            u32x4 lv = *(const u32x4*)&zl16[base];
            uint uh[4] = {hv.x, hv.y, hv.z, hv.w};
            uint ul[4] = {lv.x, lv.y, lv.z, lv.w};
            const float* wp = Wout + chunk * 8;
#pragma unroll
            for (int q2 = 0; q2 < 4; ++q2) {
                float a0 = __uint_as_float(uh[q2] << 16)
                         + __uint_as_float(ul[q2] << 16);
                float a1 = __uint_as_float(uh[q2] & 0xFFFF0000u)
                         + __uint_as_float(ul[q2] & 0xFFFF0000u);
                accf = fmaf(a0, wp[q2 * 2], accf);
                accf = fmaf(a1, wp[q2 * 2 + 1], accf);
            }
        }
        psum[qd * 64 + p] = accf;
    }
    __syncthreads();
    if (tid < PTSB) {
        out[p0 + tid] = boutp[0] + psum[tid] + psum[64 + tid]
                                 + psum[128 + tid] + psum[192 + tid];
    }
}

// ---------------------------------------------------------------------------
extern "C" void kernel_launch(void* const* d_in, const int* in_sizes, int n_in,
                              void* d_out, int out_size, void* d_ws, size_t ws_size,
                              hipStream_t stream) {
    (void)in_sizes; (void)n_in; (void)out_size; (void)ws_size;
    const float* x     = (const float*)d_in[0];
    const float* a     = (const float*)d_in[1];
    const float* Wftr  = (const float*)d_in[2];
    const float* bftr  = (const float*)d_in[3];
    const float* Wfwd  = (const float*)d_in[4];
    const float* bfwd  = (const float*)d_in[5];
    const float* Wcode = (const float*)d_in[6];
    const float* bcode = (const float*)d_in[7];
    const float* Wout  = (const float*)d_in[8];
    const float* bout  = (const float*)d_in[9];

    float* out   = (float*)d_out;                    // [B*N]
    float* out_x = out + NPTS;                       // [B*N*2]
    float*  cterm = (float*)d_ws;                    // 5120 floats
    ushort* wfB = (ushort*)(cterm + DEPTH * BATCH * HIDDEN);  // 49152 ushorts
    ushort* gwB = wfB + 49152;                                // 81920 ushorts

    // SH normalization coefficients on host (deterministic per call)
    CoefTab ct;
    for (int s = 0; s < 6; ++s)
        for (int yk = 0; yk < 9; ++yk) {
            int mm = yk - 4, am = mm < 0 ? -mm : mm, l = am + s;
            double ratio = 1.0;
            for (int q = l - am + 1; q <= l + am; ++q) ratio *= (double)q;
            double norm = sqrt((2.0 * l + 1.0) / (4.0 * M_PI * ratio));
            double cf = (mm == 0) ? norm : ((am & 1) ? -1.0 : 1.0) * sqrt(2.0) * norm;
            ct.c[s * 9 + yk] = (float)cf;
        }

    int nprep = DEPTH * BATCH + 192 + 320;
    sinr_prep<<<nprep, BLOCK, 0, stream>>>(a, Wcode, bcode, bfwd, Wftr, bftr,
                                           Wfwd, ct, cterm, wfB, gwB);
    sinr_main<<<NPTS / PTSB, BLOCK, 0, stream>>>(
        x, wfB, gwB, cterm, Wout, bout, out, out_x);
}